// Round 6
// baseline (923.269 us; speedup 1.0000x reference)
//
#include <hip/hip_runtime.h>
#include <math.h>

#define NCH     129
#define NT      250
#define DINNER  256
#define DSTATE  16
#define NHEADS  4
#define DPROJ   548   // z(256) + xh(256) + B(16) + C(16) + dt(4)
#define TC      16    // timesteps per chunk; 250 = 15*16 + 10
#define MT      35    // global M tiles of 16 (560 >= 548)
#define KS4     4     // K steps of 32 (c=0..127); c=128 via VALU
#define ZR      17    // zxbuf col stride (16 cols + 1 pad)
#define XK      136   // xh/xl row stride in shorts (16B-aligned)
#define LTILES  11    // per-head local M tiles: 4 z + 4 x + 2 BC + 1 dt
#define LROWS   (LTILES * 16)

typedef __attribute__((ext_vector_type(8))) short short8;
typedef __attribute__((ext_vector_type(4))) float f32x4;

template<int N> struct IC { static constexpr int value = N; };

__device__ __forceinline__ float silu_f(float x) { return x / (1.f + __expf(-x)); }

template<int CTRL>
__device__ __forceinline__ float dstep(float v) {
    int t = __builtin_amdgcn_update_dpp(0, __float_as_int(v), CTRL, 0xF, 0xF, true);
    return v + __int_as_float(t);
}
__device__ __forceinline__ float wave_sum63(float v) {
    v = dstep<0xB1>(v);  v = dstep<0x4E>(v);  v = dstep<0x141>(v);
    v = dstep<0x140>(v); v = dstep<0x142>(v); v = dstep<0x143>(v);
    return v;   // lane 63 = total
}
__device__ __forceinline__ float rdlane(float v, int l) {
    return __uint_as_float(__builtin_amdgcn_readlane(__float_as_uint(v), l));
}
__device__ __forceinline__ unsigned short f2bf(float f) {   // RNE
    unsigned u = __float_as_uint(f);
    u += 0x7FFF + ((u >> 16) & 1);
    return (unsigned short)(u >> 16);
}
__device__ __forceinline__ float bf2f(unsigned short h) {
    return __uint_as_float(((unsigned)h) << 16);
}

// ---------- prep: W2t[c][j] = in_proj_w @ mixer_w (fused); bias2[j] ----------
__global__ __launch_bounds__(256) void k_prep_w2(const float* __restrict__ in_proj_w,
                                                 const float* __restrict__ mixer_w,
                                                 const float* __restrict__ mixer_b,
                                                 float* __restrict__ w2t,
                                                 float* __restrict__ bias2) {
    int j = blockIdx.x;
    int c = threadIdx.x;
    if (c < NCH) {
        float acc = 0.f;
        for (int d = 0; d < 128; ++d)
            acc += in_proj_w[j * 128 + d] * mixer_w[d * NCH + c];
        w2t[(size_t)c * DPROJ + j] = acc;
    } else if (c == NCH) {
        float acc = 0.f;
        for (int d = 0; d < 128; ++d)
            acc += in_proj_w[j * 128 + d] * mixer_b[d];
        bias2[j] = acc;
    }
}

// ---------- prep: v[i] = head_w @ out_proj_w ----------
__global__ __launch_bounds__(256) void k_prep_v(const float* __restrict__ head_w,
                                                const float* __restrict__ out_proj_w,
                                                float* __restrict__ v) {
    int i = threadIdx.x;
    float acc = 0.f;
    for (int d = 0; d < 128; ++d)
        acc += head_w[d] * out_proj_w[(size_t)d * DINNER + i];
    v[i] = acc;
}

// ---------- prep: split-bf16 A-frags of W2 (KS4 k-steps, c<128), 16x16x32 layout ----------
__global__ __launch_bounds__(64) void k_prep_frag(const float* __restrict__ w2t,
                                                  unsigned short* __restrict__ ahi,
                                                  unsigned short* __restrict__ alo) {
    int mt = blockIdx.x, ks = blockIdx.y;
    int lane = threadIdx.x;
    int m = mt * 16 + (lane & 15);
    size_t base = (((size_t)(mt * KS4 + ks)) * 64 + lane) * 8;
    for (int i = 0; i < 8; ++i) {
        int k = ks * 32 + (lane >> 4) * 8 + i;   // < 128 always
        float v = (m < DPROJ) ? w2t[(size_t)k * DPROJ + m] : 0.f;
        unsigned short hb = f2bf(v);
        ahi[base + i] = hb;
        alo[base + i] = f2bf(v - bf2f(hb));
    }
}

// ---------- fused: 1 (batch, head) per block, 256 thr = 4 waves, 4 blocks/CU --
// wave (bid&3): scan (64 channels of the head + B/C conv + dt, per-lane);
// other 3 waves: per-head GEMM (11 local tiles) + x staging.
// RMS partials per (b,t,h) go to global acc; k_out folds heads -> output.
__global__ __launch_bounds__(256, 4) void k_fused(
    const float* __restrict__ x,        // [B,129,250]
    const unsigned short* __restrict__ ahi,
    const unsigned short* __restrict__ alo,
    const float* __restrict__ w2t,      // [129,548] (row 128 used)
    const float* __restrict__ bias2,
    const float* __restrict__ conv_w,
    const float* __restrict__ conv_b,
    const float* __restrict__ dt_bias,
    const float* __restrict__ A_log,
    const float* __restrict__ Dv,
    const float* __restrict__ norm_w,
    const float* __restrict__ vv,
    float* __restrict__ accb)           // [B][NT][4][2] (s1,s2) per head
{
    __shared__ short xh[TC * XK];             // bf16-hi of x chunk, [tt][k]
    __shared__ short xl[TC * XK];             // bf16-lo
    __shared__ float x128buf[2][TC];          // c=128 raw, [parity][tt]
    __shared__ float zxbuf[LROWS * ZR];       // [local row][tt]
    __shared__ float bcbuf[TC][32];           // [tt][0..15 B | 16..31 C]

    const int bid  = blockIdx.x;
    const int b    = bid >> 2;
    const int h    = bid & 3;                 // head; also the scan-wave slot
    const int tid  = threadIdx.x;
    const int lane = tid & 63;
    const int wv   = tid >> 6;                // 0..3
    const int swv  = bid & 3;                 // rotate scan wave across SIMDs
    const bool isScan = (wv == swv);
    const int gidx = (wv < swv) ? wv : wv - 1;   // 0..2 for GEMM waves
    const int sid  = gidx * 64 + lane;           // 0..191 staging index
    const int tcol = lane & 15;
    const int quad = lane >> 4;

    const float* w128 = w2t + (size_t)128 * DPROJ;
    const float* xb   = x + (size_t)b * NCH * NT;

    // per-lane params (scan wave)
    float bz = 0.f, w1z = 0.f, bx = 0.f, w1x = 0.f;
    float cw0 = 0.f, cw1 = 0.f, cw2 = 0.f, cw3 = 0.f, ccb = 0.f;
    float bx2 = 0.f, w1x2 = 0.f, dw0 = 0.f, dw1 = 0.f, dw2 = 0.f, dw3 = 0.f, dcb = 0.f;
    float bdt = 0.f, wdt = 0.f, dtb = 0.f, Ah = 0.f, Dh = 0.f, nv = 0.f;
    if (isScan) {
        int p = 64 * h + lane;                 // global channel
        bz = bias2[p];             w1z = w128[p];
        bx = bias2[DINNER + p];    w1x = w128[DINNER + p];
        cw0 = conv_w[p * 4 + 0]; cw1 = conv_w[p * 4 + 1];
        cw2 = conv_w[p * 4 + 2]; cw3 = conv_w[p * 4 + 3];
        ccb = conv_b[p];
        Dh  = Dv[h];
        nv  = norm_w[p] * vv[p];
        if (lane < 32) {                        // B/C channel conv state owner
            int q = lane, ch = DINNER + q;
            bx2  = bias2[2 * DINNER + q];
            w1x2 = w128[2 * DINNER + q];
            dw0 = conv_w[ch * 4 + 0]; dw1 = conv_w[ch * 4 + 1];
            dw2 = conv_w[ch * 4 + 2]; dw3 = conv_w[ch * 4 + 3];
            dcb = conv_b[ch];
        }
        bdt = bias2[544 + h];  wdt = w128[544 + h];
        dtb = dt_bias[h];      Ah  = -expf(A_log[h]);
    }

    float za[TC], xa[TC], dAr[TC], dxr[TC], hs[DSTATE];
    float c1 = 0.f, c2 = 0.f, c3 = 0.f;        // own x-channel conv state
    float d1 = 0.f, d2 = 0.f, d3 = 0.f;        // B/C channel conv state
#pragma unroll
    for (int n = 0; n < DSTATE; ++n) hs[n] = 0.f;

    float2 pr[6];

    auto load_chunk = [&](int t0, auto Lc) {
        constexpr int L  = decltype(Lc)::value;
        constexpr int HP = L / 2;
        constexpr int PAIRS = NCH * HP;
#pragma unroll
        for (int k = 0; k * 192 < PAIRS; ++k) {
            int u = sid + 192 * k;
            if (u < PAIRS) {
                int c = u / HP, tp = u - c * HP;
                pr[k] = *(const float2*)(xb + c * NT + t0 + 2 * tp);
            }
        }
    };
    auto store_chunk = [&](auto Lc, int par) {
        constexpr int L  = decltype(Lc)::value;
        constexpr int HP = L / 2;
        constexpr int PAIRS = NCH * HP;
#pragma unroll
        for (int k = 0; k * 192 < PAIRS; ++k) {
            int u = sid + 192 * k;
            if (u < PAIRS) {
                int c = u / HP, tp = u - c * HP;
                float2 v = pr[k];
                if (c < 128) {
                    int row = 2 * tp;
                    unsigned short h0 = f2bf(v.x), h1 = f2bf(v.y);
                    xh[row * XK + c]       = (short)h0;
                    xh[(row + 1) * XK + c] = (short)h1;
                    xl[row * XK + c]       = (short)f2bf(v.x - bf2f(h0));
                    xl[(row + 1) * XK + c] = (short)f2bf(v.y - bf2f(h1));
                } else {
                    x128buf[par][2 * tp]     = v.x;
                    x128buf[par][2 * tp + 1] = v.y;
                }
            }
        }
    };

    // prologue: stage chunk 0 (parity 0)
    if (!isScan) { load_chunk(0, IC<TC>{}); store_chunk(IC<TC>{}, 0); }
    __syncthreads();

    auto stage = [&](auto CLc, auto NLc, int s) {
        constexpr int CL = decltype(CLc)::value;
        constexpr int NL = decltype(NLc)::value;
        const int cur = s & 1;

        // ------- P1: per-head MFMA GEMM (11 local tiles over 3 waves) -------
        if (!isScan) {
            short8 bh[KS4], bl[KS4];
#pragma unroll
            for (int ks = 0; ks < KS4; ++ks) {
                bh[ks] = *(const short8*)&xh[tcol * XK + ks * 32 + quad * 8];
                bl[ks] = *(const short8*)&xl[tcol * XK + ks * 32 + quad * 8];
            }
            if constexpr (NL > 0) load_chunk((s + 1) * TC, IC<NL>{});
#pragma unroll 1
            for (int lt = gidx; lt < LTILES; lt += 3) {
                int gt = (lt < 4) ? (4 * h + lt)
                                  : ((lt < 8) ? (16 + 4 * h + (lt - 4))
                                              : (32 + (lt - 8)));
                f32x4 a0 = {0.f, 0.f, 0.f, 0.f};
                f32x4 a1 = {0.f, 0.f, 0.f, 0.f};
#pragma unroll
                for (int ks = 0; ks < KS4; ++ks) {
                    size_t fo = (((size_t)(gt * KS4 + ks)) * 64 + lane) * 8;
                    short8 ah = *(const short8*)(ahi + fo);
                    short8 al = *(const short8*)(alo + fo);
                    a0 = __builtin_amdgcn_mfma_f32_16x16x32_bf16(ah, bh[ks], a0, 0, 0, 0);
                    a1 = __builtin_amdgcn_mfma_f32_16x16x32_bf16(ah, bl[ks], a1, 0, 0, 0);
                    a1 = __builtin_amdgcn_mfma_f32_16x16x32_bf16(al, bh[ks], a1, 0, 0, 0);
                }
#pragma unroll
                for (int r = 0; r < 4; ++r)
                    zxbuf[(lt * 16 + quad * 4 + r) * ZR + tcol] = a0[r] + a1[r];
            }
        }
        __syncthreads();   // A: zxbuf ready; xh/xl consumed

        // ------- P2a: conv + silu + dt (scan wave) | restage (GEMM waves) ---
        if (isScan) {
#pragma unroll
            for (int tt = 0; tt < CL; ++tt) {
                float xm = x128buf[cur][tt];
                float zraw = zxbuf[lane * ZR + tt] + bz + w1z * xm;
                float xraw = zxbuf[(64 + lane) * ZR + tt] + bx + w1x * xm;
                float cv = fmaf(cw3, xraw, fmaf(cw2, c1, fmaf(cw1, c2, fmaf(cw0, c3, ccb))));
                c3 = c2; c2 = c1; c1 = xraw;
                xa[tt] = silu_f(cv);
                za[tt] = silu_f(zraw);
                if (lane < 32) {
                    float r2 = zxbuf[(128 + lane) * ZR + tt] + bx2 + w1x2 * xm;
                    float cv2 = fmaf(dw3, r2, fmaf(dw2, d1, fmaf(dw1, d2, fmaf(dw0, d3, dcb))));
                    d3 = d2; d2 = d1; d1 = r2;
                    bcbuf[tt][lane] = silu_f(cv2);
                }
                float dval = zxbuf[(160 + h) * ZR + tt] + bdt + wdt * xm + dtb;
                float dtv  = (dval > 20.f) ? dval : log1pf(expf(dval));
                dAr[tt] = __expf(dtv * Ah);
                dxr[tt] = dtv * xa[tt];
            }
        } else {
            if constexpr (NL > 0) store_chunk(IC<NL>{}, (s + 1) & 1);
        }
        __syncthreads();   // B: bc/dt ready; xh/xl restaged

        // ------- P2b: scan + DPP reductions (overlaps next P1) --------------
        if (isScan) {
#pragma unroll
            for (int tt = 0; tt < CL; ++tt) {
                float xv  = xa[tt];
                float g   = za[tt];
                float dAv = dAr[tt];
                float dx  = dxr[tt];
                float bcv = bcbuf[tt][lane & 31];
                float y0 = 0.f, y1 = 0.f, y2 = 0.f, y3 = 0.f;
#pragma unroll
                for (int n = 0; n < 4; ++n) {
                    float b0 = rdlane(bcv, n),      cc0 = rdlane(bcv, DSTATE + n);
                    float b1 = rdlane(bcv, 4 + n),  cc1 = rdlane(bcv, DSTATE + 4 + n);
                    float b2v = rdlane(bcv, 8 + n), cc2 = rdlane(bcv, DSTATE + 8 + n);
                    float b3 = rdlane(bcv, 12 + n), cc3 = rdlane(bcv, DSTATE + 12 + n);
                    hs[n]      = fmaf(hs[n],      dAv, dx * b0);  y0 = fmaf(hs[n],      cc0, y0);
                    hs[4 + n]  = fmaf(hs[4 + n],  dAv, dx * b1);  y1 = fmaf(hs[4 + n],  cc1, y1);
                    hs[8 + n]  = fmaf(hs[8 + n],  dAv, dx * b2v); y2 = fmaf(hs[8 + n],  cc2, y2);
                    hs[12 + n] = fmaf(hs[12 + n], dAv, dx * b3);  y3 = fmaf(hs[12 + n], cc3, y3);
                }
                float val = fmaf(Dh, xv, (y0 + y1) + (y2 + y3)) * g;
                float s1 = wave_sum63(val * val);
                float s2 = wave_sum63(val * nv);
                if (lane == 63) {
                    int t = s * TC + tt;
                    float2 o; o.x = s1; o.y = s2;
                    *(float2*)(accb + (((size_t)b * NT + t) * 4 + h) * 2) = o;
                }
            }
        }
        // no barrier: next P1 (zxbuf/xh writes) disjoint from P2b reads
    };

#pragma unroll 1
    for (int s = 0; s <= 13; ++s) stage(IC<16>{}, IC<16>{}, s);
    stage(IC<16>{}, IC<10>{}, 14);
    stage(IC<10>{}, IC<0>{}, 15);
}

// ---------- fold heads: out[b] = head_b + mean_t( s2 / rms(s1) ) ----------
__global__ __launch_bounds__(64) void k_out(const float* __restrict__ accb,
                                            const float* __restrict__ head_b,
                                            float* __restrict__ out) {
    int b = blockIdx.x, lane = threadIdx.x;
    float local = 0.f;
#pragma unroll
    for (int k = 0; k < 4; ++k) {
        int t = lane + 64 * k;
        if (t < NT) {
            const float* a = accb + ((size_t)b * NT + t) * 8;
            float s1 = (a[0] + a[2]) + (a[4] + a[6]);
            float s2 = (a[1] + a[3]) + (a[5] + a[7]);
            local += s2 * rsqrtf(fmaf(s1, 1.f / DINNER, 1e-5f));
        }
    }
    float tot = wave_sum63(local);
    if (lane == 63) out[b] = head_b[0] + tot * (1.f / NT);
}

extern "C" void kernel_launch(void* const* d_in, const int* in_sizes, int n_in,
                              void* d_out, int out_size, void* d_ws, size_t ws_size,
                              hipStream_t stream) {
    const float* x         = (const float*)d_in[0];
    const float* mixer_w   = (const float*)d_in[1];
    const float* mixer_b   = (const float*)d_in[2];
    const float* in_proj_w = (const float*)d_in[3];
    const float* conv_w    = (const float*)d_in[4];
    const float* conv_b    = (const float*)d_in[5];
    const float* dt_bias   = (const float*)d_in[6];
    const float* A_log     = (const float*)d_in[7];
    const float* Dp        = (const float*)d_in[8];
    const float* norm_w    = (const float*)d_in[9];
    const float* out_proj_w= (const float*)d_in[10];
    const float* head_w    = (const float*)d_in[11];
    const float* head_b    = (const float*)d_in[12];
    float* out = (float*)d_out;

    int B = in_sizes[0] / (NCH * NT);   // 512

    float* ws    = (float*)d_ws;
    float* w2t   = ws;                          // 129*548 f32
    float* bias2 = w2t + (size_t)NCH * DPROJ;
    float* vvp   = bias2 + DPROJ;
    unsigned short* ahi = (unsigned short*)(vvp + DINNER);       // 35*4*64*8 shorts
    unsigned short* alo = ahi + (size_t)MT * KS4 * 64 * 8;
    float* accb  = (float*)(alo + (size_t)MT * KS4 * 64 * 8);    // B*NT*4*2 f32 (4 MB)

    k_prep_w2<<<DPROJ, 256, 0, stream>>>(in_proj_w, mixer_w, mixer_b, w2t, bias2);
    k_prep_v<<<1, 256, 0, stream>>>(head_w, out_proj_w, vvp);
    k_prep_frag<<<dim3(MT, KS4), 64, 0, stream>>>(w2t, ahi, alo);
    k_fused<<<B * 4, 256, 0, stream>>>(x, ahi, alo, w2t, bias2, conv_w, conv_b,
                                       dt_bias, A_log, Dp, norm_w, vvp, accb);
    k_out<<<B, 64, 0, stream>>>(accb, head_b, out);
}

// Round 7
// 440.995 us; speedup vs baseline: 2.0936x; 2.0936x over previous
//
#include <hip/hip_runtime.h>
#include <math.h>

#define NCH     129
#define NT      250
#define DINNER  256
#define DSTATE  16
#define NHEADS  4
#define DPROJ   548   // z(256) + xh(256) + B(16) + C(16) + dt(4)
#define TC      8     // timesteps per chunk; 250 = 31*8 + 2
#define MT      35    // M tiles of 16 (560 >= 548)
#define KS4     4     // K steps of 32 (c=0..127); c=128 via VALU
#define ZR      17    // zxbuf col stride (16 cols + 1 pad)
#define XK      136   // xh/xl row stride in shorts (16B-aligned)

typedef __attribute__((ext_vector_type(8))) short short8;
typedef __attribute__((ext_vector_type(4))) float f32x4;

template<int N> struct IC { static constexpr int value = N; };

__device__ __forceinline__ float silu_f(float x) { return x / (1.f + __expf(-x)); }

template<int CTRL>
__device__ __forceinline__ float dstep(float v) {
    int t = __builtin_amdgcn_update_dpp(0, __float_as_int(v), CTRL, 0xF, 0xF, true);
    return v + __int_as_float(t);
}
__device__ __forceinline__ float wave_sum63(float v) {
    v = dstep<0xB1>(v);  v = dstep<0x4E>(v);  v = dstep<0x141>(v);
    v = dstep<0x140>(v); v = dstep<0x142>(v); v = dstep<0x143>(v);
    return v;   // lane 63 = total
}
__device__ __forceinline__ float rdlane(float v, int l) {
    return __uint_as_float(__builtin_amdgcn_readlane(__float_as_uint(v), l));
}
__device__ __forceinline__ unsigned short f2bf(float f) {   // RNE
    unsigned u = __float_as_uint(f);
    u += 0x7FFF + ((u >> 16) & 1);
    return (unsigned short)(u >> 16);
}
__device__ __forceinline__ float bf2f(unsigned short h) {
    return __uint_as_float(((unsigned)h) << 16);
}

// ---------- prep: W2t[c][j] = in_proj_w @ mixer_w (fused); bias2[j] ----------
__global__ __launch_bounds__(256) void k_prep_w2(const float* __restrict__ in_proj_w,
                                                 const float* __restrict__ mixer_w,
                                                 const float* __restrict__ mixer_b,
                                                 float* __restrict__ w2t,
                                                 float* __restrict__ bias2) {
    int j = blockIdx.x;
    int c = threadIdx.x;
    if (c < NCH) {
        float acc = 0.f;
        for (int d = 0; d < 128; ++d)
            acc += in_proj_w[j * 128 + d] * mixer_w[d * NCH + c];
        w2t[(size_t)c * DPROJ + j] = acc;
    } else if (c == NCH) {
        float acc = 0.f;
        for (int d = 0; d < 128; ++d)
            acc += in_proj_w[j * 128 + d] * mixer_b[d];
        bias2[j] = acc;
    }
}

// ---------- prep: v[i] = head_w @ out_proj_w ----------
__global__ __launch_bounds__(256) void k_prep_v(const float* __restrict__ head_w,
                                                const float* __restrict__ out_proj_w,
                                                float* __restrict__ v) {
    int i = threadIdx.x;
    float acc = 0.f;
    for (int d = 0; d < 128; ++d)
        acc += head_w[d] * out_proj_w[(size_t)d * DINNER + i];
    v[i] = acc;
}

// ---------- prep: split-bf16 A-frags of W2 (KS4 k-steps, c<128), 16x16x32 layout ----------
__global__ __launch_bounds__(64) void k_prep_frag(const float* __restrict__ w2t,
                                                  unsigned short* __restrict__ ahi,
                                                  unsigned short* __restrict__ alo) {
    int mt = blockIdx.x, ks = blockIdx.y;
    int lane = threadIdx.x;
    int m = mt * 16 + (lane & 15);
    size_t base = (((size_t)(mt * KS4 + ks)) * 64 + lane) * 8;
    for (int i = 0; i < 8; ++i) {
        int k = ks * 32 + (lane >> 4) * 8 + i;   // < 128 always
        float v = (m < DPROJ) ? w2t[(size_t)k * DPROJ + m] : 0.f;
        unsigned short hb = f2bf(v);
        ahi[base + i] = hb;
        alo[base + i] = f2bf(v - bf2f(hb));
    }
}

// ---------- fused: 2 batches/block, 640 thr = 10 waves ----------
// waves 0-3: batch0 channels; waves 4-7: batch1 channels; waves 8,9: aux for b0,b1.
// P1 change vs 348us baseline: all 8 A-loads of a tile issued up front as named
// scalars (one vmcnt drain/tile instead of four) + a1 split into two accumulators
// (three independent 4-deep MFMA chains) -> removes the per-ks latency serialization.
__global__ __launch_bounds__(640, 2) void k_fused(
    const float* __restrict__ x,        // [B,129,250]
    const unsigned short* __restrict__ ahi,
    const unsigned short* __restrict__ alo,
    const float* __restrict__ w2t,      // [129,548] (row 128 used)
    const float* __restrict__ bias2,
    const float* __restrict__ conv_w,
    const float* __restrict__ conv_b,
    const float* __restrict__ dt_bias,
    const float* __restrict__ A_log,
    const float* __restrict__ Dv,
    const float* __restrict__ norm_w,
    const float* __restrict__ vv,
    const float* __restrict__ head_b,
    float* __restrict__ out)
{
    __shared__ short xh[16 * XK];             // bf16-hi of x chunk, [col][k]
    __shared__ short xl[16 * XK];             // bf16-lo
    __shared__ float x128buf[2][2][TC];       // c=128 raw, [parity][batch][tt]
    __shared__ float zxbuf[DPROJ * ZR];       // [j][col], col = b*8+tt
    __shared__ float bcbuf[2][TC][32];        // [batch][tt][0..15 B | 16..31 C]
    __shared__ float dtbuf[2][TC][NHEADS];
    __shared__ float dAbuf[2][TC][NHEADS];
    __shared__ float smp[2][2][TC][8];        // [parity][batch][tt][2w(+1)]

    const int b2   = blockIdx.x;
    const int tid  = threadIdx.x;
    const int lane = tid & 63;
    const int wv   = tid >> 6;                // 0..9
    const bool isMain = (wv < 8);
    const int mb   = isMain ? (wv >> 2) : (wv - 8);
    const int p    = ((wv & 3) << 6) | lane;  // main channel (valid if isMain)
    const int q    = lane;
    const int tcol = lane & 15;
    const int quad = lane >> 4;
    const bool isFold = isMain && ((wv & 3) == 0);   // waves 0 (b0) and 4 (b1)

    const float* w128 = w2t + (size_t)128 * DPROJ;

    float bz = 0.f, bx = 0.f, w1z = 0.f, w1x = 0.f;
    float cw0 = 0.f, cw1 = 0.f, cw2 = 0.f, cw3 = 0.f, ccb = 0.f;
    float dtb = 0.f, Ah = 0.f, Dh = 0.f, nv = 0.f;
    if (isMain) {
        bz = bias2[p];          w1z = w128[p];
        bx = bias2[DINNER + p]; w1x = w128[DINNER + p];
        cw0 = conv_w[p * 4 + 0]; cw1 = conv_w[p * 4 + 1];
        cw2 = conv_w[p * 4 + 2]; cw3 = conv_w[p * 4 + 3];
        ccb = conv_b[p];
        Dh = Dv[p >> 6];
        nv = norm_w[p] * vv[p];
    } else if (q < 36) {
        bx  = bias2[2 * DINNER + q];
        w1x = w128[2 * DINNER + q];
        if (q < 32) {
            int ch = DINNER + q;
            cw0 = conv_w[ch * 4 + 0]; cw1 = conv_w[ch * 4 + 1];
            cw2 = conv_w[ch * 4 + 2]; cw3 = conv_w[ch * 4 + 3];
            ccb = conv_b[ch];
        } else {
            int h = q - 32;
            dtb = dt_bias[h];
            Ah  = -expf(A_log[h]);
        }
    }

    float za[TC], xa[TC], hs[DSTATE];
    float c1 = 0.f, c2 = 0.f, c3 = 0.f, outacc = 0.f;
#pragma unroll
    for (int n = 0; n < DSTATE; ++n) hs[n] = 0.f;

    const float* xb_aux = x + ((size_t)2 * b2 + mb) * NCH * NT;  // aux's batch
    const int hh = wv & 3;                                       // head (main)
    float2 pr[9];

    auto load_chunk = [&](int t0, auto Lc) {
        constexpr int L  = decltype(Lc)::value;
        constexpr int HP = (L >= 2) ? L / 2 : 1;
        constexpr int PAIRS = NCH * HP;
#pragma unroll
        for (int k = 0; k * 64 < PAIRS; ++k) {
            int u = lane + 64 * k;
            if (u < PAIRS) {
                int c = u / HP, tp = u - c * HP;
                pr[k] = *(const float2*)(xb_aux + c * NT + t0 + 2 * tp);
            }
        }
    };
    auto store_chunk = [&](auto Lc, int nxtpar) {
        constexpr int L  = decltype(Lc)::value;
        constexpr int HP = (L >= 2) ? L / 2 : 1;
        constexpr int PAIRS = NCH * HP;
#pragma unroll
        for (int k = 0; k * 64 < PAIRS; ++k) {
            int u = lane + 64 * k;
            if (u < PAIRS) {
                int c = u / HP, tp = u - c * HP;
                float2 v = pr[k];
                if (c < 128) {
                    int row = mb * 8 + 2 * tp;
                    unsigned short h0 = f2bf(v.x), h1 = f2bf(v.y);
                    xh[row * XK + c]       = (short)h0;
                    xh[(row + 1) * XK + c] = (short)h1;
                    xl[row * XK + c]       = (short)f2bf(v.x - bf2f(h0));
                    xl[(row + 1) * XK + c] = (short)f2bf(v.y - bf2f(h1));
                } else {
                    x128buf[nxtpar][mb][2 * tp]     = v.x;
                    x128buf[nxtpar][mb][2 * tp + 1] = v.y;
                }
            }
        }
    };

    // prologue: stage chunk 0 (parity 0)
    if (!isMain) { load_chunk(0, IC<TC>{}); store_chunk(IC<TC>{}, 0); }
    __syncthreads();

    auto stage = [&](auto CLc, auto NLc, int s) {
        constexpr int CL = decltype(CLc)::value;
        constexpr int NL = decltype(NLc)::value;
        const int cur = s & 1;

        // ---------------- P1: MFMA GEMM ----------------
        if (isMain) {
            short8 bh[KS4], bl[KS4];
#pragma unroll
            for (int ks = 0; ks < KS4; ++ks) {
                bh[ks] = *(const short8*)&xh[tcol * XK + ks * 32 + quad * 8];
                bl[ks] = *(const short8*)&xl[tcol * XK + ks * 32 + quad * 8];
            }
#pragma unroll 1
            for (int mt = wv; mt < MT; mt += 8) {
                const unsigned short* ap = ahi + (((size_t)(mt * KS4)) * 64 + lane) * 8;
                const unsigned short* lp = alo + (((size_t)(mt * KS4)) * 64 + lane) * 8;
                // issue all 8 independent A-loads up front (one latency exposure)
                short8 A0 = *(const short8*)(ap);
                short8 A1 = *(const short8*)(ap + 512);
                short8 A2 = *(const short8*)(ap + 1024);
                short8 A3 = *(const short8*)(ap + 1536);
                short8 L0 = *(const short8*)(lp);
                short8 L1 = *(const short8*)(lp + 512);
                short8 L2 = *(const short8*)(lp + 1024);
                short8 L3 = *(const short8*)(lp + 1536);
                f32x4 a0 = {0.f, 0.f, 0.f, 0.f};
                f32x4 a1 = {0.f, 0.f, 0.f, 0.f};
                f32x4 a2 = {0.f, 0.f, 0.f, 0.f};
                // three independent 4-deep MFMA chains
                a0 = __builtin_amdgcn_mfma_f32_16x16x32_bf16(A0, bh[0], a0, 0, 0, 0);
                a1 = __builtin_amdgcn_mfma_f32_16x16x32_bf16(A0, bl[0], a1, 0, 0, 0);
                a2 = __builtin_amdgcn_mfma_f32_16x16x32_bf16(L0, bh[0], a2, 0, 0, 0);
                a0 = __builtin_amdgcn_mfma_f32_16x16x32_bf16(A1, bh[1], a0, 0, 0, 0);
                a1 = __builtin_amdgcn_mfma_f32_16x16x32_bf16(A1, bl[1], a1, 0, 0, 0);
                a2 = __builtin_amdgcn_mfma_f32_16x16x32_bf16(L1, bh[1], a2, 0, 0, 0);
                a0 = __builtin_amdgcn_mfma_f32_16x16x32_bf16(A2, bh[2], a0, 0, 0, 0);
                a1 = __builtin_amdgcn_mfma_f32_16x16x32_bf16(A2, bl[2], a1, 0, 0, 0);
                a2 = __builtin_amdgcn_mfma_f32_16x16x32_bf16(L2, bh[2], a2, 0, 0, 0);
                a0 = __builtin_amdgcn_mfma_f32_16x16x32_bf16(A3, bh[3], a0, 0, 0, 0);
                a1 = __builtin_amdgcn_mfma_f32_16x16x32_bf16(A3, bl[3], a1, 0, 0, 0);
                a2 = __builtin_amdgcn_mfma_f32_16x16x32_bf16(L3, bh[3], a2, 0, 0, 0);
#pragma unroll
                for (int r = 0; r < 4; ++r) {
                    int j = mt * 16 + quad * 4 + r;
                    if (j < DPROJ) zxbuf[j * ZR + tcol] = a0[r] + (a1[r] + a2[r]);
                }
            }
        } else {
            if constexpr (NL > 0) load_chunk((s + 1) * TC, IC<NL>{});
        }
        __syncthreads();   // A: zxbuf ready; xh/xl consumed

        // ---------------- P2a ----------------
        if (isMain) {
            if (isFold && s > 0 && lane < TC) {   // fold prev chunk's partials
                const float* sp = smp[(s - 1) & 1][mb][lane];
                float s1 = sp[0] + sp[2] + sp[4] + sp[6];
                float s2 = sp[1] + sp[3] + sp[5] + sp[7];
                outacc = fmaf(s2, rsqrtf(fmaf(s1, 1.f / DINNER, 1e-5f)), outacc);
            }
#pragma unroll
            for (int tt = 0; tt < CL; ++tt) {
                float xm = x128buf[cur][mb][tt];
                int col = mb * 8 + tt;
                float zraw = zxbuf[p * ZR + col] + bz + w1z * xm;
                float xraw = zxbuf[(DINNER + p) * ZR + col] + bx + w1x * xm;
                float cv = fmaf(cw3, xraw, fmaf(cw2, c1, fmaf(cw1, c2, fmaf(cw0, c3, ccb))));
                c3 = c2; c2 = c1; c1 = xraw;
                xa[tt] = silu_f(cv);
                za[tt] = silu_f(zraw);
            }
        } else {
            if constexpr (NL > 0) store_chunk(IC<NL>{}, (s + 1) & 1);
            if (q < 32) {
#pragma unroll
                for (int tt = 0; tt < CL; ++tt) {
                    float xm = x128buf[cur][mb][tt];
                    float raw = zxbuf[(2 * DINNER + q) * ZR + mb * 8 + tt] + bx + w1x * xm;
                    float cv = fmaf(cw3, raw, fmaf(cw2, c1, fmaf(cw1, c2, fmaf(cw0, c3, ccb))));
                    c3 = c2; c2 = c1; c1 = raw;
                    bcbuf[mb][tt][q] = silu_f(cv);
                }
            } else if (q < 36) {
                int h = q - 32;
#pragma unroll
                for (int tt = 0; tt < CL; ++tt) {
                    float xm = x128buf[cur][mb][tt];
                    float val = zxbuf[(544 + h) * ZR + mb * 8 + tt] + bx + w1x * xm + dtb;
                    float dt = (val > 20.f) ? val : log1pf(expf(val));
                    dtbuf[mb][tt][h] = dt;
                    dAbuf[mb][tt][h] = __expf(dt * Ah);
                }
            }
        }
        __syncthreads();   // B: bc/dt ready; xh/xl restaged

        // ---------------- P2b: scan + DPP reductions ----------------
        if (isMain) {
#pragma unroll
            for (int tt = 0; tt < CL; ++tt) {
                float xv  = xa[tt];
                float g   = za[tt];
                float dtv = dtbuf[mb][tt][hh];
                float dAv = dAbuf[mb][tt][hh];
                float bcv = bcbuf[mb][tt][lane & 31];
                float dx = dtv * xv;
                float y0 = 0.f, y1 = 0.f, y2 = 0.f, y3 = 0.f;
#pragma unroll
                for (int n = 0; n < 4; ++n) {
                    float b0 = rdlane(bcv, n),      cc0 = rdlane(bcv, DSTATE + n);
                    float b1 = rdlane(bcv, 4 + n),  cc1 = rdlane(bcv, DSTATE + 4 + n);
                    float b2v = rdlane(bcv, 8 + n), cc2 = rdlane(bcv, DSTATE + 8 + n);
                    float b3 = rdlane(bcv, 12 + n), cc3 = rdlane(bcv, DSTATE + 12 + n);
                    hs[n]      = fmaf(hs[n],      dAv, dx * b0);  y0 = fmaf(hs[n],      cc0, y0);
                    hs[4 + n]  = fmaf(hs[4 + n],  dAv, dx * b1);  y1 = fmaf(hs[4 + n],  cc1, y1);
                    hs[8 + n]  = fmaf(hs[8 + n],  dAv, dx * b2v); y2 = fmaf(hs[8 + n],  cc2, y2);
                    hs[12 + n] = fmaf(hs[12 + n], dAv, dx * b3);  y3 = fmaf(hs[12 + n], cc3, y3);
                }
                float val = fmaf(Dh, xv, (y0 + y1) + (y2 + y3)) * g;
                float s1 = wave_sum63(val * val);
                float s2 = wave_sum63(val * nv);
                if (lane == 63) {
                    smp[cur][mb][tt][2 * (wv & 3)]     = s1;
                    smp[cur][mb][tt][2 * (wv & 3) + 1] = s2;
                }
            }
        }
        // no barrier here: next P1 doesn't touch smp/bcbuf; zxbuf reads done pre-B
    };

    stage(IC<8>{}, IC<8>{}, 0);
    for (int s = 1; s <= 29; ++s) stage(IC<8>{}, IC<8>{}, s);
    stage(IC<8>{}, IC<2>{}, 30);
    stage(IC<2>{}, IC<0>{}, 31);
    __syncthreads();

    if (isFold) {
        if (lane < 2) {   // fold tail chunk (stage 31, parity 1, CL=2)
            const float* sp = smp[1][mb][lane];
            float s1 = sp[0] + sp[2] + sp[4] + sp[6];
            float s2 = sp[1] + sp[3] + sp[5] + sp[7];
            outacc = fmaf(s2, rsqrtf(fmaf(s1, 1.f / DINNER, 1e-5f)), outacc);
        }
        float tot = wave_sum63(outacc);
        if (lane == 63) out[2 * b2 + mb] = head_b[0] + tot * (1.f / NT);
    }
}

extern "C" void kernel_launch(void* const* d_in, const int* in_sizes, int n_in,
                              void* d_out, int out_size, void* d_ws, size_t ws_size,
                              hipStream_t stream) {
    const float* x         = (const float*)d_in[0];
    const float* mixer_w   = (const float*)d_in[1];
    const float* mixer_b   = (const float*)d_in[2];
    const float* in_proj_w = (const float*)d_in[3];
    const float* conv_w    = (const float*)d_in[4];
    const float* conv_b    = (const float*)d_in[5];
    const float* dt_bias   = (const float*)d_in[6];
    const float* A_log     = (const float*)d_in[7];
    const float* Dp        = (const float*)d_in[8];
    const float* norm_w    = (const float*)d_in[9];
    const float* out_proj_w= (const float*)d_in[10];
    const float* head_w    = (const float*)d_in[11];
    const float* head_b    = (const float*)d_in[12];
    float* out = (float*)d_out;

    int B = in_sizes[0] / (NCH * NT);   // 512

    float* ws    = (float*)d_ws;
    float* w2t   = ws;                          // 129*548 f32
    float* bias2 = w2t + (size_t)NCH * DPROJ;
    float* vvp   = bias2 + DPROJ;
    unsigned short* ahi = (unsigned short*)(vvp + DINNER);       // 35*4*64*8 shorts
    unsigned short* alo = ahi + (size_t)MT * KS4 * 64 * 8;

    k_prep_w2<<<DPROJ, 256, 0, stream>>>(in_proj_w, mixer_w, mixer_b, w2t, bias2);
    k_prep_v<<<1, 256, 0, stream>>>(head_w, out_proj_w, vvp);
    k_prep_frag<<<dim3(MT, KS4), 64, 0, stream>>>(w2t, ahi, alo);
    k_fused<<<B / 2, 640, 0, stream>>>(x, ahi, alo, w2t, bias2, conv_w, conv_b,
                                       dt_bias, A_log, Dp, norm_w, vvp, head_b, out);
}

// Round 8
// 431.245 us; speedup vs baseline: 2.1409x; 1.0226x over previous
//
#include <hip/hip_runtime.h>
#include <math.h>

#define NCH     129
#define NT      250
#define DINNER  256
#define DSTATE  16
#define NHEADS  4
#define DPROJ   548   // z(256) + xh(256) + B(16) + C(16) + dt(4)
#define TC      8     // fused fallback: timesteps per chunk
#define MT      35    // M tiles of 16 (560 >= 548)
#define KS4     4     // K steps of 32 (c=0..127); c=128 via VALU
#define ZR      17    // fused zxbuf col stride
#define XK      136   // xh/xl row stride in shorts (16B-aligned)
#define ZXR     560   // split-path zx row stride (floats), 16B-mult
#define GZR     33    // gemm LDS zxb col stride (32 cols + 1 pad)

typedef __attribute__((ext_vector_type(8))) short short8;
typedef __attribute__((ext_vector_type(4))) float f32x4;

template<int N> struct IC { static constexpr int value = N; };

__device__ __forceinline__ float silu_f(float x) { return x / (1.f + __expf(-x)); }

template<int CTRL>
__device__ __forceinline__ float dstep(float v) {
    int t = __builtin_amdgcn_update_dpp(0, __float_as_int(v), CTRL, 0xF, 0xF, true);
    return v + __int_as_float(t);
}
__device__ __forceinline__ float wave_sum63(float v) {
    v = dstep<0xB1>(v);  v = dstep<0x4E>(v);  v = dstep<0x141>(v);
    v = dstep<0x140>(v); v = dstep<0x142>(v); v = dstep<0x143>(v);
    return v;   // lane 63 = total
}
__device__ __forceinline__ float rdlane(float v, int l) {
    return __uint_as_float(__builtin_amdgcn_readlane(__float_as_uint(v), l));
}
__device__ __forceinline__ unsigned short f2bf(float f) {   // RNE
    unsigned u = __float_as_uint(f);
    u += 0x7FFF + ((u >> 16) & 1);
    return (unsigned short)(u >> 16);
}
__device__ __forceinline__ float bf2f(unsigned short h) {
    return __uint_as_float(((unsigned)h) << 16);
}

// ---------- prep: W2t[c][j] = in_proj_w @ mixer_w (fused); bias2[j] ----------
__global__ __launch_bounds__(256) void k_prep_w2(const float* __restrict__ in_proj_w,
                                                 const float* __restrict__ mixer_w,
                                                 const float* __restrict__ mixer_b,
                                                 float* __restrict__ w2t,
                                                 float* __restrict__ bias2) {
    int j = blockIdx.x;
    int c = threadIdx.x;
    if (c < NCH) {
        float acc = 0.f;
        for (int d = 0; d < 128; ++d)
            acc += in_proj_w[j * 128 + d] * mixer_w[d * NCH + c];
        w2t[(size_t)c * DPROJ + j] = acc;
    } else if (c == NCH) {
        float acc = 0.f;
        for (int d = 0; d < 128; ++d)
            acc += in_proj_w[j * 128 + d] * mixer_b[d];
        bias2[j] = acc;
    }
}

// ---------- prep: v[i] = head_w @ out_proj_w ----------
__global__ __launch_bounds__(256) void k_prep_v(const float* __restrict__ head_w,
                                                const float* __restrict__ out_proj_w,
                                                float* __restrict__ v) {
    int i = threadIdx.x;
    float acc = 0.f;
    for (int d = 0; d < 128; ++d)
        acc += head_w[d] * out_proj_w[(size_t)d * DINNER + i];
    v[i] = acc;
}

// ---------- prep: split-bf16 A-frags of W2 (KS4 k-steps, c<128), 16x16x32 layout ----------
__global__ __launch_bounds__(64) void k_prep_frag(const float* __restrict__ w2t,
                                                  unsigned short* __restrict__ ahi,
                                                  unsigned short* __restrict__ alo) {
    int mt = blockIdx.x, ks = blockIdx.y;
    int lane = threadIdx.x;
    int m = mt * 16 + (lane & 15);
    size_t base = (((size_t)(mt * KS4 + ks)) * 64 + lane) * 8;
    for (int i = 0; i < 8; ++i) {
        int k = ks * 32 + (lane >> 4) * 8 + i;   // < 128 always
        float v = (m < DPROJ) ? w2t[(size_t)k * DPROJ + m] : 0.f;
        unsigned short hb = f2bf(v);
        ahi[base + i] = hb;
        alo[base + i] = f2bf(v - bf2f(hb));
    }
}

// =================== SPLIT PATH: kernel 1 — projection GEMM ===================
// One block = (batch, 32-timestep tile). 512 thr = 8 waves. Computes the raw
// 548x32 projection (c<128 K-dim; bias & c=128 handled by k_scan) and writes
// f32 to zx[b][t][560]. M split in two halves so LDS stays ~55KB (2 blocks/CU).
__global__ __launch_bounds__(512, 2) void k_gemm(
    const float* __restrict__ x,
    const unsigned short* __restrict__ ahi,
    const unsigned short* __restrict__ alo,
    float* __restrict__ zx)
{
    __shared__ short xh[32 * XK];
    __shared__ short xl[32 * XK];
    __shared__ float zxb[288 * GZR];   // half of M at a time (288 rows)

    const int b   = blockIdx.x;
    const int t0  = blockIdx.y * 32;
    const int TV  = (NT - t0 < 32) ? (NT - t0) : 32;   // 32 or 26
    const int tid = threadIdx.x;
    const int lane = tid & 63;
    const int wv   = tid >> 6;
    const int tcol = lane & 15;
    const int quad = lane >> 4;

    const float* xb = x + (size_t)b * NCH * NT;

    // ---- stage x (c<128) as split-bf16 into xh/xl ----
    auto stg = [&](auto HPc) {
        constexpr int HP = decltype(HPc)::value;
        constexpr int PAIRS = 128 * HP;
#pragma unroll
        for (int k = 0; k * 512 < PAIRS; ++k) {
            int u = tid + 512 * k;
            if (u < PAIRS) {
                int c = u / HP, tp = u - c * HP;
                float2 v = *(const float2*)(xb + c * NT + t0 + 2 * tp);
                int row = 2 * tp;
                unsigned short h0 = f2bf(v.x), h1 = f2bf(v.y);
                xh[row * XK + c]       = (short)h0;
                xh[(row + 1) * XK + c] = (short)h1;
                xl[row * XK + c]       = (short)f2bf(v.x - bf2f(h0));
                xl[(row + 1) * XK + c] = (short)f2bf(v.y - bf2f(h1));
            }
        }
    };
    if (TV == 32) stg(IC<16>{}); else stg(IC<13>{});
    __syncthreads();

    float* orow = zx + ((size_t)b * NT + t0) * ZXR;

    auto gemm_half = [&](int mt0, int mt1, int rbase) {
        for (int mt = mt0 + wv; mt < mt1; mt += 8) {
            size_t fo = (((size_t)(mt * KS4)) * 64 + lane) * 8;
            const unsigned short* ap = ahi + fo;
            const unsigned short* lp = alo + fo;
            short8 A0 = *(const short8*)(ap);
            short8 A1 = *(const short8*)(ap + 512);
            short8 A2 = *(const short8*)(ap + 1024);
            short8 A3 = *(const short8*)(ap + 1536);
            short8 L0 = *(const short8*)(lp);
            short8 L1 = *(const short8*)(lp + 512);
            short8 L2 = *(const short8*)(lp + 1024);
            short8 L3 = *(const short8*)(lp + 1536);
            f32x4 a0 = {0.f, 0.f, 0.f, 0.f};
            f32x4 a1 = {0.f, 0.f, 0.f, 0.f};
#pragma unroll
            for (int ks = 0; ks < KS4; ++ks) {
                short8 Ak = (ks == 0) ? A0 : (ks == 1) ? A1 : (ks == 2) ? A2 : A3;
                short8 Lk = (ks == 0) ? L0 : (ks == 1) ? L1 : (ks == 2) ? L2 : L3;
                short8 bh = *(const short8*)&xh[tcol * XK + ks * 32 + quad * 8];
                short8 bl = *(const short8*)&xl[tcol * XK + ks * 32 + quad * 8];
                a0 = __builtin_amdgcn_mfma_f32_16x16x32_bf16(Ak, bh, a0, 0, 0, 0);
                a0 = __builtin_amdgcn_mfma_f32_16x16x32_bf16(Ak, bl, a0, 0, 0, 0);
                a0 = __builtin_amdgcn_mfma_f32_16x16x32_bf16(Lk, bh, a0, 0, 0, 0);
            }
#pragma unroll
            for (int ks = 0; ks < KS4; ++ks) {
                short8 Ak = (ks == 0) ? A0 : (ks == 1) ? A1 : (ks == 2) ? A2 : A3;
                short8 Lk = (ks == 0) ? L0 : (ks == 1) ? L1 : (ks == 2) ? L2 : L3;
                short8 bh = *(const short8*)&xh[(16 + tcol) * XK + ks * 32 + quad * 8];
                short8 bl = *(const short8*)&xl[(16 + tcol) * XK + ks * 32 + quad * 8];
                a1 = __builtin_amdgcn_mfma_f32_16x16x32_bf16(Ak, bh, a1, 0, 0, 0);
                a1 = __builtin_amdgcn_mfma_f32_16x16x32_bf16(Ak, bl, a1, 0, 0, 0);
                a1 = __builtin_amdgcn_mfma_f32_16x16x32_bf16(Lk, bh, a1, 0, 0, 0);
            }
#pragma unroll
            for (int r = 0; r < 4; ++r) {
                int j = mt * 16 + quad * 4 + r;
                if (j < DPROJ) {
                    int lr = j - rbase;
                    zxb[lr * GZR + tcol]      = a0[r];
                    zxb[lr * GZR + 16 + tcol] = a1[r];
                }
            }
        }
    };

    // half 0: rows 0..287 (tiles 0..17)
    gemm_half(0, 18, 0);
    __syncthreads();
    for (int idx = tid; idx < 288 * TV; idx += 512) {
        int t = idx / 288, j = idx - t * 288;
        orow[(size_t)t * ZXR + j] = zxb[j * GZR + t];
    }
    __syncthreads();
    // half 1: rows 288..547 (tiles 18..34)
    gemm_half(18, 35, 288);
    __syncthreads();
    for (int idx = tid; idx < 260 * TV; idx += 512) {
        int t = idx / 260, jj = idx - t * 260;
        orow[(size_t)t * ZXR + 288 + jj] = zxb[jj * GZR + t];
    }
}

// =================== SPLIT PATH: kernel 2 — conv + scan =======================
// One block = one batch; 4 waves = 4 heads. Lane = channel within head.
// B/C conv lives in lanes<32 of every wave (redundant across heads, cheap);
// broadcast via v_readlane (no LDS). Cross-head RMS fold every 16 t via tiny LDS.
__global__ __launch_bounds__(256, 4) void k_scan(
    const float* __restrict__ zx,
    const float* __restrict__ x,
    const float* __restrict__ w2t,
    const float* __restrict__ bias2,
    const float* __restrict__ conv_w,
    const float* __restrict__ conv_b,
    const float* __restrict__ dt_bias,
    const float* __restrict__ A_log,
    const float* __restrict__ Dv,
    const float* __restrict__ norm_w,
    const float* __restrict__ vv,
    const float* __restrict__ head_b,
    float* __restrict__ out)
{
    __shared__ float smp[2][16][4][2];

    const int b    = blockIdx.x;
    const int tid  = threadIdx.x;
    const int lane = tid & 63;
    const int h    = tid >> 6;

    const float* w128 = w2t + (size_t)128 * DPROJ;
    const int p = 64 * h + lane;

    const float bz  = bias2[p],           w1z = w128[p];
    const float bx  = bias2[DINNER + p],  w1x = w128[DINNER + p];
    const float cw0 = conv_w[p * 4 + 0], cw1 = conv_w[p * 4 + 1];
    const float cw2 = conv_w[p * 4 + 2], cw3 = conv_w[p * 4 + 3];
    const float ccb = conv_b[p];
    const float Dh  = Dv[h];
    const float nv  = norm_w[p] * vv[p];
    float bx2 = 0.f, w1x2 = 0.f, dw0 = 0.f, dw1 = 0.f, dw2 = 0.f, dw3 = 0.f, dcb = 0.f;
    if (lane < 32) {
        int q = lane, ch = DINNER + q;
        bx2  = bias2[2 * DINNER + q];
        w1x2 = w128[2 * DINNER + q];
        dw0 = conv_w[ch * 4 + 0]; dw1 = conv_w[ch * 4 + 1];
        dw2 = conv_w[ch * 4 + 2]; dw3 = conv_w[ch * 4 + 3];
        dcb = conv_b[ch];
    }
    const float bdt = bias2[544 + h], wdt = w128[544 + h];
    const float dtb = dt_bias[h];
    const float Ah  = -expf(A_log[h]);

    float hs[DSTATE];
#pragma unroll
    for (int n = 0; n < DSTATE; ++n) hs[n] = 0.f;
    float c1 = 0.f, c2 = 0.f, c3 = 0.f;
    float d1 = 0.f, d2 = 0.f, d3 = 0.f;
    float outacc = 0.f;

    const float* zrow = zx + (size_t)b * NT * ZXR;
    const float* xmp  = x + ((size_t)b * NCH + 128) * NT;

    // preload t=0
    float pz  = zrow[p];
    float px  = zrow[256 + p];
    float pbc = (lane < 32) ? zrow[512 + lane] : 0.f;
    float pdt = zrow[544 + h];
    float pxm = xmp[0];

    int t = 0;
    for (int s = 0; s < 16; ++s) {
        const int CL  = (s < 15) ? 16 : 10;
        const int par = s & 1;
        for (int tt = 0; tt < CL; ++tt, ++t) {
            // prefetch t+1 (hides L3/HBM latency under this t's compute)
            float nz = 0.f, nx = 0.f, nbc = 0.f, ndt = 0.f, nxm = 0.f;
            if (t + 1 < NT) {
                const float* r = zrow + (size_t)(t + 1) * ZXR;
                nz  = r[p];
                nx  = r[256 + p];
                nbc = (lane < 32) ? r[512 + lane] : 0.f;
                ndt = r[544 + h];
                nxm = xmp[t + 1];
            }
            const float xm = pxm;
            const float g  = silu_f(pz + bz + w1z * xm);
            const float xraw = px + bx + w1x * xm;
            float cv = fmaf(cw3, xraw, fmaf(cw2, c1, fmaf(cw1, c2, fmaf(cw0, c3, ccb))));
            c3 = c2; c2 = c1; c1 = xraw;
            const float xa = silu_f(cv);
            float bcs;
            {
                float r2  = pbc + bx2 + w1x2 * xm;
                float cv2 = fmaf(dw3, r2, fmaf(dw2, d1, fmaf(dw1, d2, fmaf(dw0, d3, dcb))));
                d3 = d2; d2 = d1; d1 = r2;
                bcs = silu_f(cv2);          // meaningful in lanes 0..31 only
            }
            float dval = pdt + bdt + wdt * xm + dtb;
            float dtv  = (dval > 20.f) ? dval : log1pf(expf(dval));
            float dAv  = __expf(dtv * Ah);
            float dx   = dtv * xa;

            float y0 = 0.f, y1 = 0.f, y2 = 0.f, y3 = 0.f;
#pragma unroll
            for (int n = 0; n < 4; ++n) {
                float b0  = rdlane(bcs, n),      cc0 = rdlane(bcs, DSTATE + n);
                float b1v = rdlane(bcs, 4 + n),  cc1 = rdlane(bcs, DSTATE + 4 + n);
                float b2v = rdlane(bcs, 8 + n),  cc2 = rdlane(bcs, DSTATE + 8 + n);
                float b3v = rdlane(bcs, 12 + n), cc3 = rdlane(bcs, DSTATE + 12 + n);
                hs[n]      = fmaf(hs[n],      dAv, dx * b0);  y0 = fmaf(hs[n],      cc0, y0);
                hs[4 + n]  = fmaf(hs[4 + n],  dAv, dx * b1v); y1 = fmaf(hs[4 + n],  cc1, y1);
                hs[8 + n]  = fmaf(hs[8 + n],  dAv, dx * b2v); y2 = fmaf(hs[8 + n],  cc2, y2);
                hs[12 + n] = fmaf(hs[12 + n], dAv, dx * b3v); y3 = fmaf(hs[12 + n], cc3, y3);
            }
            float val = fmaf(Dh, xa, (y0 + y1) + (y2 + y3)) * g;
            float s1 = wave_sum63(val * val);
            float s2 = wave_sum63(val * nv);
            if (lane == 63) {
                smp[par][tt][h][0] = s1;
                smp[par][tt][h][1] = s2;
            }
            pz = nz; px = nx; pbc = nbc; pdt = ndt; pxm = nxm;
        }
        __syncthreads();
        if (h == 0 && lane < CL) {
            float t1 = (smp[par][lane][0][0] + smp[par][lane][1][0]) +
                       (smp[par][lane][2][0] + smp[par][lane][3][0]);
            float t2 = (smp[par][lane][0][1] + smp[par][lane][1][1]) +
                       (smp[par][lane][2][1] + smp[par][lane][3][1]);
            outacc = fmaf(t2, rsqrtf(fmaf(t1, 1.f / DINNER, 1e-5f)), outacc);
        }
    }
    if (h == 0) {
        float tot = wave_sum63(outacc);
        if (lane == 63) out[b] = head_b[0] + tot * (1.f / NT);
    }
}

// =================== FALLBACK: fused kernel (proven 357us) ====================
__global__ __launch_bounds__(640, 2) void k_fused(
    const float* __restrict__ x,
    const unsigned short* __restrict__ ahi,
    const unsigned short* __restrict__ alo,
    const float* __restrict__ w2t,
    const float* __restrict__ bias2,
    const float* __restrict__ conv_w,
    const float* __restrict__ conv_b,
    const float* __restrict__ dt_bias,
    const float* __restrict__ A_log,
    const float* __restrict__ Dv,
    const float* __restrict__ norm_w,
    const float* __restrict__ vv,
    const float* __restrict__ head_b,
    float* __restrict__ out)
{
    __shared__ short xh[16 * XK];
    __shared__ short xl[16 * XK];
    __shared__ float x128buf[2][2][TC];
    __shared__ float zxbuf[DPROJ * ZR];
    __shared__ float bcbuf[2][TC][32];
    __shared__ float dtbuf[2][TC][NHEADS];
    __shared__ float dAbuf[2][TC][NHEADS];
    __shared__ float smp[2][2][TC][8];

    const int b2   = blockIdx.x;
    const int tid  = threadIdx.x;
    const int lane = tid & 63;
    const int wv   = tid >> 6;
    const bool isMain = (wv < 8);
    const int mb   = isMain ? (wv >> 2) : (wv - 8);
    const int p    = ((wv & 3) << 6) | lane;
    const int q    = lane;
    const int tcol = lane & 15;
    const int quad = lane >> 4;
    const bool isFold = isMain && ((wv & 3) == 0);

    const float* w128 = w2t + (size_t)128 * DPROJ;

    float bz = 0.f, bx = 0.f, w1z = 0.f, w1x = 0.f;
    float cw0 = 0.f, cw1 = 0.f, cw2 = 0.f, cw3 = 0.f, ccb = 0.f;
    float dtb = 0.f, Ah = 0.f, Dh = 0.f, nv = 0.f;
    if (isMain) {
        bz = bias2[p];          w1z = w128[p];
        bx = bias2[DINNER + p]; w1x = w128[DINNER + p];
        cw0 = conv_w[p * 4 + 0]; cw1 = conv_w[p * 4 + 1];
        cw2 = conv_w[p * 4 + 2]; cw3 = conv_w[p * 4 + 3];
        ccb = conv_b[p];
        Dh = Dv[p >> 6];
        nv = norm_w[p] * vv[p];
    } else if (q < 36) {
        bx  = bias2[2 * DINNER + q];
        w1x = w128[2 * DINNER + q];
        if (q < 32) {
            int ch = DINNER + q;
            cw0 = conv_w[ch * 4 + 0]; cw1 = conv_w[ch * 4 + 1];
            cw2 = conv_w[ch * 4 + 2]; cw3 = conv_w[ch * 4 + 3];
            ccb = conv_b[ch];
        } else {
            int h = q - 32;
            dtb = dt_bias[h];
            Ah  = -expf(A_log[h]);
        }
    }

    float za[TC], xa[TC], hs[DSTATE];
    float c1 = 0.f, c2 = 0.f, c3 = 0.f, outacc = 0.f;
#pragma unroll
    for (int n = 0; n < DSTATE; ++n) hs[n] = 0.f;

    const float* xb_aux = x + ((size_t)2 * b2 + mb) * NCH * NT;
    const int hh = wv & 3;
    float2 pr[9];

    auto load_chunk = [&](int t0, auto Lc) {
        constexpr int L  = decltype(Lc)::value;
        constexpr int HP = (L >= 2) ? L / 2 : 1;
        constexpr int PAIRS = NCH * HP;
#pragma unroll
        for (int k = 0; k * 64 < PAIRS; ++k) {
            int u = lane + 64 * k;
            if (u < PAIRS) {
                int c = u / HP, tp = u - c * HP;
                pr[k] = *(const float2*)(xb_aux + c * NT + t0 + 2 * tp);
            }
        }
    };
    auto store_chunk = [&](auto Lc, int nxtpar) {
        constexpr int L  = decltype(Lc)::value;
        constexpr int HP = (L >= 2) ? L / 2 : 1;
        constexpr int PAIRS = NCH * HP;
#pragma unroll
        for (int k = 0; k * 64 < PAIRS; ++k) {
            int u = lane + 64 * k;
            if (u < PAIRS) {
                int c = u / HP, tp = u - c * HP;
                float2 v = pr[k];
                if (c < 128) {
                    int row = mb * 8 + 2 * tp;
                    unsigned short h0 = f2bf(v.x), h1 = f2bf(v.y);
                    xh[row * XK + c]       = (short)h0;
                    xh[(row + 1) * XK + c] = (short)h1;
                    xl[row * XK + c]       = (short)f2bf(v.x - bf2f(h0));
                    xl[(row + 1) * XK + c] = (short)f2bf(v.y - bf2f(h1));
                } else {
                    x128buf[nxtpar][mb][2 * tp]     = v.x;
                    x128buf[nxtpar][mb][2 * tp + 1] = v.y;
                }
            }
        }
    };

    if (!isMain) { load_chunk(0, IC<TC>{}); store_chunk(IC<TC>{}, 0); }
    __syncthreads();

    auto stage = [&](auto CLc, auto NLc, int s) {
        constexpr int CL = decltype(CLc)::value;
        constexpr int NL = decltype(NLc)::value;
        const int cur = s & 1;

        if (isMain) {
            short8 bh[KS4], bl[KS4];
#pragma unroll
            for (int ks = 0; ks < KS4; ++ks) {
                bh[ks] = *(const short8*)&xh[tcol * XK + ks * 32 + quad * 8];
                bl[ks] = *(const short8*)&xl[tcol * XK + ks * 32 + quad * 8];
            }
            for (int mt = wv; mt < MT; mt += 8) {
                f32x4 a0 = {0.f, 0.f, 0.f, 0.f};
                f32x4 a1 = {0.f, 0.f, 0.f, 0.f};
#pragma unroll
                for (int ks = 0; ks < KS4; ++ks) {
                    size_t fo = (((size_t)(mt * KS4 + ks)) * 64 + lane) * 8;
                    short8 ah = *(const short8*)(ahi + fo);
                    short8 al = *(const short8*)(alo + fo);
                    a0 = __builtin_amdgcn_mfma_f32_16x16x32_bf16(ah, bh[ks], a0, 0, 0, 0);
                    a1 = __builtin_amdgcn_mfma_f32_16x16x32_bf16(ah, bl[ks], a1, 0, 0, 0);
                    a1 = __builtin_amdgcn_mfma_f32_16x16x32_bf16(al, bh[ks], a1, 0, 0, 0);
                }
#pragma unroll
                for (int r = 0; r < 4; ++r) {
                    int j = mt * 16 + quad * 4 + r;
                    if (j < DPROJ) zxbuf[j * ZR + tcol] = a0[r] + a1[r];
                }
            }
        } else {
            if constexpr (NL > 0) load_chunk((s + 1) * TC, IC<NL>{});
        }
        __syncthreads();

        if (isMain) {
            if (isFold && s > 0 && lane < TC) {
                const float* sp = smp[(s - 1) & 1][mb][lane];
                float s1 = sp[0] + sp[2] + sp[4] + sp[6];
                float s2 = sp[1] + sp[3] + sp[5] + sp[7];
                outacc = fmaf(s2, rsqrtf(fmaf(s1, 1.f / DINNER, 1e-5f)), outacc);
            }
#pragma unroll
            for (int tt = 0; tt < CL; ++tt) {
                float xm = x128buf[cur][mb][tt];
                int col = mb * 8 + tt;
                float zraw = zxbuf[p * ZR + col] + bz + w1z * xm;
                float xraw = zxbuf[(DINNER + p) * ZR + col] + bx + w1x * xm;
                float cv = fmaf(cw3, xraw, fmaf(cw2, c1, fmaf(cw1, c2, fmaf(cw0, c3, ccb))));
                c3 = c2; c2 = c1; c1 = xraw;
                xa[tt] = silu_f(cv);
                za[tt] = silu_f(zraw);
            }
        } else {
            if constexpr (NL > 0) store_chunk(IC<NL>{}, (s + 1) & 1);
            if (q < 32) {
#pragma unroll
                for (int tt = 0; tt < CL; ++tt) {
                    float xm = x128buf[cur][mb][tt];
                    float raw = zxbuf[(2 * DINNER + q) * ZR + mb * 8 + tt] + bx + w1x * xm;
                    float cv = fmaf(cw3, raw, fmaf(cw2, c1, fmaf(cw1, c2, fmaf(cw0, c3, ccb))));
                    c3 = c2; c2 = c1; c1 = raw;
                    bcbuf[mb][tt][q] = silu_f(cv);
                }
            } else if (q < 36) {
                int h = q - 32;
#pragma unroll
                for (int tt = 0; tt < CL; ++tt) {
                    float xm = x128buf[cur][mb][tt];
                    float val = zxbuf[(544 + h) * ZR + mb * 8 + tt] + bx + w1x * xm + dtb;
                    float dt = (val > 20.f) ? val : log1pf(expf(val));
                    dtbuf[mb][tt][h] = dt;
                    dAbuf[mb][tt][h] = __expf(dt * Ah);
                }
            }
        }
        __syncthreads();

        if (isMain) {
#pragma unroll
            for (int tt = 0; tt < CL; ++tt) {
                float xv  = xa[tt];
                float g   = za[tt];
                float dtv = dtbuf[mb][tt][hh];
                float dAv = dAbuf[mb][tt][hh];
                float bcv = bcbuf[mb][tt][lane & 31];
                float dx = dtv * xv;
                float y0 = 0.f, y1 = 0.f, y2 = 0.f, y3 = 0.f;
#pragma unroll
                for (int n = 0; n < 4; ++n) {
                    float b0 = rdlane(bcv, n),      cc0 = rdlane(bcv, DSTATE + n);
                    float b1 = rdlane(bcv, 4 + n),  cc1 = rdlane(bcv, DSTATE + 4 + n);
                    float b2v = rdlane(bcv, 8 + n), cc2 = rdlane(bcv, DSTATE + 8 + n);
                    float b3 = rdlane(bcv, 12 + n), cc3 = rdlane(bcv, DSTATE + 12 + n);
                    hs[n]      = fmaf(hs[n],      dAv, dx * b0);  y0 = fmaf(hs[n],      cc0, y0);
                    hs[4 + n]  = fmaf(hs[4 + n],  dAv, dx * b1);  y1 = fmaf(hs[4 + n],  cc1, y1);
                    hs[8 + n]  = fmaf(hs[8 + n],  dAv, dx * b2v); y2 = fmaf(hs[8 + n],  cc2, y2);
                    hs[12 + n] = fmaf(hs[12 + n], dAv, dx * b3);  y3 = fmaf(hs[12 + n], cc3, y3);
                }
                float val = fmaf(Dh, xv, (y0 + y1) + (y2 + y3)) * g;
                float s1 = wave_sum63(val * val);
                float s2 = wave_sum63(val * nv);
                if (lane == 63) {
                    smp[cur][mb][tt][2 * (wv & 3)]     = s1;
                    smp[cur][mb][tt][2 * (wv & 3) + 1] = s2;
                }
            }
        }
    };

    stage(IC<8>{}, IC<8>{}, 0);
    for (int s = 1; s <= 29; ++s) stage(IC<8>{}, IC<8>{}, s);
    stage(IC<8>{}, IC<2>{}, 30);
    stage(IC<2>{}, IC<0>{}, 31);
    __syncthreads();

    if (isFold) {
        if (lane < 2) {
            const float* sp = smp[1][mb][lane];
            float s1 = sp[0] + sp[2] + sp[4] + sp[6];
            float s2 = sp[1] + sp[3] + sp[5] + sp[7];
            outacc = fmaf(s2, rsqrtf(fmaf(s1, 1.f / DINNER, 1e-5f)), outacc);
        }
        float tot = wave_sum63(outacc);
        if (lane == 63) out[2 * b2 + mb] = head_b[0] + tot * (1.f / NT);
    }
}

extern "C" void kernel_launch(void* const* d_in, const int* in_sizes, int n_in,
                              void* d_out, int out_size, void* d_ws, size_t ws_size,
                              hipStream_t stream) {
    const float* x         = (const float*)d_in[0];
    const float* mixer_w   = (const float*)d_in[1];
    const float* mixer_b   = (const float*)d_in[2];
    const float* in_proj_w = (const float*)d_in[3];
    const float* conv_w    = (const float*)d_in[4];
    const float* conv_b    = (const float*)d_in[5];
    const float* dt_bias   = (const float*)d_in[6];
    const float* A_log     = (const float*)d_in[7];
    const float* Dp        = (const float*)d_in[8];
    const float* norm_w    = (const float*)d_in[9];
    const float* out_proj_w= (const float*)d_in[10];
    const float* head_w    = (const float*)d_in[11];
    const float* head_b    = (const float*)d_in[12];
    float* out = (float*)d_out;

    int B = in_sizes[0] / (NCH * NT);   // 512

    float* ws    = (float*)d_ws;
    float* w2t   = ws;                          // 129*548 f32
    float* bias2 = w2t + (size_t)NCH * DPROJ;
    float* vvp   = bias2 + DPROJ;
    unsigned short* ahi = (unsigned short*)(vvp + DINNER);       // 35*4*64*8 shorts
    unsigned short* alo = ahi + (size_t)MT * KS4 * 64 * 8;

    size_t prep_end = (size_t)((char*)(alo + (size_t)MT * KS4 * 64 * 8) - (char*)d_ws);
    size_t zx_off   = (prep_end + 255) & ~(size_t)255;
    size_t need     = zx_off + (size_t)B * NT * ZXR * sizeof(float);

    k_prep_w2<<<DPROJ, 256, 0, stream>>>(in_proj_w, mixer_w, mixer_b, w2t, bias2);
    k_prep_v<<<1, 256, 0, stream>>>(head_w, out_proj_w, vvp);
    k_prep_frag<<<dim3(MT, KS4), 64, 0, stream>>>(w2t, ahi, alo);

    if (ws_size >= need) {
        float* zx = (float*)((char*)d_ws + zx_off);
        int ntiles = (NT + 31) / 32;   // 8
        k_gemm<<<dim3(B, ntiles), 512, 0, stream>>>(x, ahi, alo, zx);
        k_scan<<<B, 256, 0, stream>>>(zx, x, w2t, bias2, conv_w, conv_b, dt_bias,
                                      A_log, Dp, norm_w, vvp, head_b, out);
    } else {
        k_fused<<<B / 2, 640, 0, stream>>>(x, ahi, alo, w2t, bias2, conv_w, conv_b,
                                           dt_bias, A_log, Dp, norm_w, vvp, head_b, out);
    }
}